// Round 12
// baseline (327.781 us; speedup 1.0000x reference)
//
#include <hip/hip_runtime.h>
#include <hip/hip_bf16.h>

#define N_NODES 50000
#define N_EDGES 800000
#define IN_F    128
#define OUT_F   256
#define BN_EPS  1e-5f
#define ABLOCKS 2048
#define SCAN_NB ((N_NODES + 1023) / 1024)   // 49

typedef float float4_ __attribute__((ext_vector_type(4)));
typedef float f32x4 __attribute__((ext_vector_type(4)));
typedef float f32x8 __attribute__((ext_vector_type(8)));
typedef short bf16x8 __attribute__((ext_vector_type(8)));
typedef unsigned int uint4_ __attribute__((ext_vector_type(4)));

// ---------------- CSR build ----------------

__global__ void count_kernel(const int* __restrict__ dst, int* __restrict__ cnt, int e) {
    int i = blockIdx.x * blockDim.x + threadIdx.x;
    if (i < e) atomicAdd(&cnt[dst[i]], 1);
}

// hierarchical scan, level 1: per-block (1024 elems) exclusive prefix + block total
__global__ __launch_bounds__(256) void scan1_kernel(const int* __restrict__ cnt,
        int* __restrict__ excl, int* __restrict__ blocksum, int n) {
    __shared__ int wsum[4];
    int tid = threadIdx.x;
    int lane = tid & 63, wv = tid >> 6;
    int base = blockIdx.x * 1024 + tid * 4;
    int v0 = (base + 0 < n) ? cnt[base + 0] : 0;
    int v1 = (base + 1 < n) ? cnt[base + 1] : 0;
    int v2 = (base + 2 < n) ? cnt[base + 2] : 0;
    int v3 = (base + 3 < n) ? cnt[base + 3] : 0;
    int t = v0 + v1 + v2 + v3;
    int s = t;
    #pragma unroll
    for (int d = 1; d < 64; d <<= 1) {
        int o = __shfl_up(s, d, 64);
        if (lane >= d) s += o;
    }
    if (lane == 63) wsum[wv] = s;
    __syncthreads();
    int woff = 0;
    #pragma unroll
    for (int w = 0; w < 4; w++) woff += (w < wv) ? wsum[w] : 0;
    int off = woff + s - t;   // exclusive prefix for this thread's first elem
    if (base + 0 < n) excl[base + 0] = off;
    if (base + 1 < n) excl[base + 1] = off + v0;
    if (base + 2 < n) excl[base + 2] = off + v0 + v1;
    if (base + 3 < n) excl[base + 3] = off + v0 + v1 + v2;
    if (tid == 255) blocksum[blockIdx.x] = woff + s;
}

// level 2+3 fused: every block redundantly wave-scans the 49 block sums,
// then emits rowptr/cursor/dinv.
__global__ __launch_bounds__(256) void scan3_kernel(const int* __restrict__ cnt,
        const int* __restrict__ excl, const int* __restrict__ blocksum,
        int* __restrict__ rowptr, int* __restrict__ cursor, float* __restrict__ dinv, int n) {
    __shared__ int boff_s, total_s;
    int tid = threadIdx.x;
    if (tid < 64) {
        int v = (tid < SCAN_NB) ? blocksum[tid] : 0;
        int s = v;
        #pragma unroll
        for (int d = 1; d < 64; d <<= 1) {
            int o = __shfl_up(s, d, 64);
            if (tid >= d) s += o;
        }
        if (tid == (blockIdx.x >> 2)) boff_s = s - v;   // this block's 1024-chunk offset
        if (tid == SCAN_NB - 1) total_s = s;
    }
    __syncthreads();
    int i = blockIdx.x * 256 + tid;
    if (i < n) {
        int r = excl[i] + boff_s;
        rowptr[i] = r;
        cursor[i] = r;
        dinv[i] = rsqrtf((float)(cnt[i] + 1));
    }
    if (i == 0) rowptr[n] = total_s;
}

__global__ void fill_kernel(const int* __restrict__ src, const int* __restrict__ dst,
                            int* __restrict__ cursor, int* __restrict__ col, int e) {
    int i = blockIdx.x * blockDim.x + threadIdx.x;
    if (i < e) {
        int d = dst[i];
        int pos = atomicAdd(&cursor[d], 1);
        col[pos] = src[i];
    }
}

// ---------------- bf16 helpers ----------------

__device__ inline unsigned short f2bf(float f) {
    union { float f; unsigned int u; } a; a.f = f;
    unsigned int u = a.u;
    unsigned int r = (u + 0x7FFFu + ((u >> 16) & 1u)) >> 16;
    return (unsigned short)r;
}

// ---------------- W / Wp pack for MFMA B-operand ----------------
// wpk[((kb*16 + nt)*64 + lane)*8 + j] = bf16( W[kb*32 + (lane>>4)*8 + j][nt*16 + (lane&15)] )
// B-frag layout for mfma_f32_16x16x32_bf16: lane l holds B[k=(l>>4)*8+j][col=l&15].

__global__ void pack_kernel(const float* __restrict__ W, const float* __restrict__ Wp,
                            unsigned short* __restrict__ wpk, unsigned short* __restrict__ wppk) {
    int b = blockIdx.x;   // 32 blocks: 0-15 -> W, 16-31 -> Wp
    const float* src = (b < 16) ? W : Wp;
    unsigned short* dst = (b < 16) ? wpk : wppk;
    int base = (b & 15) * 2048;
    for (int t = threadIdx.x; t < 2048; t += 256) {
        int idx = base + t;
        int j = idx & 7, l = (idx >> 3) & 63, nt = (idx >> 9) & 15, kb = idx >> 13;
        int k = kb * 32 + ((l >> 4) << 3) + j;
        int c = (nt << 4) + (l & 15);
        dst[idx] = f2bf(src[k * 256 + c]);
    }
}

// ---------------- MFMA GEMM: wave = 16 rows x 256 cols, K=128 ----------------
// MODE 0: hs[r][c] = bf16( dinv[r] * (x@W)[r][c] )
// MODE 1: out[r][c] = relu( out[r][c]*scale[c] + shift[c] ) + (x@Wp)[r][c]   (in-place)

template <int MODE>
__global__ __launch_bounds__(256) void mgemm_kernel(
    const float* __restrict__ X, const unsigned short* __restrict__ wpk,
    const float* __restrict__ dinv, unsigned short* __restrict__ hs,
    const float* __restrict__ ss, float* __restrict__ out)
{
    int wv = threadIdx.x >> 6;
    int lane = threadIdx.x & 63;
    int r0 = blockIdx.x * 64 + wv * 16;
    if (r0 >= N_NODES) return;

    int arow = min(r0 + (lane & 15), N_NODES - 1);
    int kbase = (lane >> 4) << 3;   // 0,8,16,24

    union Frag { bf16x8 v; unsigned int u[4]; uint4_ q; };

    // load + convert A fragments (once per wave, reused across all 16 n-tiles)
    Frag af[4];
    const float* xrow = X + (size_t)arow * IN_F + kbase;
    #pragma unroll
    for (int kb = 0; kb < 4; kb++) {
        float4_ p0 = *(const float4_*)(xrow + kb * 32);
        float4_ p1 = *(const float4_*)(xrow + kb * 32 + 4);
        af[kb].u[0] = (unsigned int)f2bf(p0[0]) | ((unsigned int)f2bf(p0[1]) << 16);
        af[kb].u[1] = (unsigned int)f2bf(p0[2]) | ((unsigned int)f2bf(p0[3]) << 16);
        af[kb].u[2] = (unsigned int)f2bf(p1[0]) | ((unsigned int)f2bf(p1[1]) << 16);
        af[kb].u[3] = (unsigned int)f2bf(p1[2]) | ((unsigned int)f2bf(p1[3]) << 16);
    }

    int rb = r0 + ((lane >> 4) << 2);   // C/D row base for this lane
    float dv[4];
    if (MODE == 0) {
        #pragma unroll
        for (int g = 0; g < 4; g++) dv[g] = dinv[min(rb + g, N_NODES - 1)];
    }

    for (int nt = 0; nt < 16; nt++) {
        f32x4 acc = (f32x4){0.f, 0.f, 0.f, 0.f};
        #pragma unroll
        for (int kb = 0; kb < 4; kb++) {
            Frag bf;
            bf.q = *(const uint4_*)(wpk + (((kb * 16 + nt) * 64 + lane) << 3));
            acc = __builtin_amdgcn_mfma_f32_16x16x32_bf16(af[kb].v, bf.v, acc, 0, 0, 0);
        }
        int colb = (nt << 4) + (lane & 15);
        if (MODE == 0) {
            #pragma unroll
            for (int g = 0; g < 4; g++) {
                int r = rb + g;
                if (r < N_NODES) hs[(size_t)r * OUT_F + colb] = f2bf(acc[g] * dv[g]);
            }
        } else {
            float sc = ss[colb], sh = ss[OUT_F + colb];
            #pragma unroll
            for (int g = 0; g < 4; g++) {
                int r = rb + g;
                if (r < N_NODES) {
                    float* p = out + (size_t)r * OUT_F + colb;
                    float v = *p;
                    *p = fmaxf(v * sc + sh, 0.f) + acc[g];
                }
            }
        }
    }
}

// ---------------- CSR aggregation ----------------
// 1 wave per node; half-wave gather (lanes 0-31 / 32-63 take interleaved neighbors,
// 16 B/lane), then an in-wave permute so the output store is lane-contiguous
// (lane l writes feats [4l, 4l+4) -> one ordered 1 KB run per wave, full-line writes).
// Fused BN partial stats -> partialT[col][block] (transposed for coalesced stats2).

__global__ __launch_bounds__(256) void agg_kernel(
    const unsigned short* __restrict__ hrow, const int* __restrict__ rowptr,
    const int* __restrict__ col, const float* __restrict__ dinv,
    float* __restrict__ out, float* __restrict__ partialT, int nwaves_total)
{
    __shared__ float lds_s[4][512];
    int wv = threadIdx.x >> 6;
    int wid = blockIdx.x * 4 + wv;
    int lane = threadIdx.x & 63;
    int half = lane >> 5, li = lane & 31;

    f32x8 psum = (f32x8){0.f,0.f,0.f,0.f,0.f,0.f,0.f,0.f};
    f32x8 pssq = (f32x8){0.f,0.f,0.f,0.f,0.f,0.f,0.f,0.f};

    auto load8 = [&](int r) -> f32x8 {
        uint4_ q = *(const uint4_*)(hrow + (size_t)r * 256 + li * 8);
        f32x8 f;
        f[0] = __uint_as_float(q[0] << 16);
        f[1] = __uint_as_float(q[0] & 0xFFFF0000u);
        f[2] = __uint_as_float(q[1] << 16);
        f[3] = __uint_as_float(q[1] & 0xFFFF0000u);
        f[4] = __uint_as_float(q[2] << 16);
        f[5] = __uint_as_float(q[2] & 0xFFFF0000u);
        f[6] = __uint_as_float(q[3] << 16);
        f[7] = __uint_as_float(q[3] & 0xFFFF0000u);
        return f;
    };

    for (int i = wid; i < N_NODES; i += nwaves_total) {
        f32x8 a0 = (f32x8){0.f,0.f,0.f,0.f,0.f,0.f,0.f,0.f};
        f32x8 a1 = (f32x8){0.f,0.f,0.f,0.f,0.f,0.f,0.f,0.f};
        int rs = rowptr[i], re = rowptr[i + 1];
        if (half == 0) a1 = load8(i);   // self-loop term
        int j = rs + half;
        for (; j + 2 < re; j += 4) {    // this half's neighbors: rs+half, +2, +4, ...
            a0 += load8(col[j]);
            a1 += load8(col[j + 2]);
        }
        if (j < re) a0 += load8(col[j]);
        a0 += a1;
        // combine the two halves (both end up with the full row sum)
        f32x8 c;
        #pragma unroll
        for (int k = 0; k < 8; k++) c[k] = a0[k] + __shfl_xor(a0[k], 32, 64);
        float dv = dinv[i];
        c *= dv;
        psum += c;
        pssq += c * c;
        // permute so lane l holds feats [4l, 4l+4): source lane = l>>1, half-select by l&1
        float tmp[8];
        #pragma unroll
        for (int k = 0; k < 8; k++) tmp[k] = __shfl(c[k], lane >> 1, 64);
        int sel = (lane & 1) << 2;
        float4_ wvec = (float4_){tmp[sel + 0], tmp[sel + 1], tmp[sel + 2], tmp[sel + 3]};
        *(float4_*)(out + (size_t)i * OUT_F + lane * 4) = wvec;
    }

    // per-wave stats into LDS (half 0 holds the valid copy)
    if (half == 0) {
        #pragma unroll
        for (int k = 0; k < 8; k++) {
            lds_s[wv][li * 8 + k] = psum[k];
            lds_s[wv][256 + li * 8 + k] = pssq[k];
        }
    }
    __syncthreads();
    int t = threadIdx.x;
    float s0 = lds_s[0][t] + lds_s[1][t] + lds_s[2][t] + lds_s[3][t];
    float s1 = lds_s[0][256 + t] + lds_s[1][256 + t] + lds_s[2][256 + t] + lds_s[3][256 + t];
    partialT[(size_t)t * ABLOCKS + blockIdx.x] = s0;
    partialT[(size_t)(256 + t) * ABLOCKS + blockIdx.x] = s1;
}

// ---------------- BN stats reduce: block f -> ss[f], ss[256+f] ----------------

__global__ __launch_bounds__(256) void stats2_kernel(const float* __restrict__ partialT,
        const float* __restrict__ gamma, const float* __restrict__ beta,
        float* __restrict__ ss) {
    int f = blockIdx.x;
    int t = threadIdx.x;
    float ps = 0.f, qs = 0.f;
    for (int r = t; r < ABLOCKS; r += 256) {
        ps += partialT[(size_t)f * ABLOCKS + r];
        qs += partialT[(size_t)(256 + f) * ABLOCKS + r];
    }
    __shared__ float rs_[256], rq_[256];
    rs_[t] = ps; rq_[t] = qs;
    __syncthreads();
    for (int off = 128; off > 0; off >>= 1) {
        if (t < off) { rs_[t] += rs_[t + off]; rq_[t] += rq_[t + off]; }
        __syncthreads();
    }
    if (t == 0) {
        float mean = rs_[0] / (float)N_NODES;
        float var = rq_[0] / (float)N_NODES - mean * mean;
        float inv = rsqrtf(var + BN_EPS);
        float sc = gamma[f] * inv;
        ss[f] = sc;
        ss[256 + f] = beta[f] - mean * sc;
    }
}

// ---------------- launch ----------------

extern "C" void kernel_launch(void* const* d_in, const int* in_sizes, int n_in,
                              void* d_out, int out_size, void* d_ws, size_t ws_size,
                              hipStream_t stream) {
    const float* x     = (const float*)d_in[0];
    const int*   ei    = (const int*)d_in[1];
    const float* W     = (const float*)d_in[2];
    // d_in[3] = b : cancels under BatchNorm, unused
    const float* gamma = (const float*)d_in[4];
    const float* beta  = (const float*)d_in[5];
    const float* Wp    = (const float*)d_in[6];
    float* out = (float*)d_out;

    char* wsp = (char*)d_ws;
    size_t off = 0;
    auto alloc = [&](size_t sz) -> void* {
        void* p = wsp + off;
        off += (sz + 255) & ~(size_t)255;
        return p;
    };
    int*   cnt      = (int*)alloc((size_t)N_NODES * 4);
    int*   rowptr   = (int*)alloc((size_t)(N_NODES + 1) * 4);
    int*   cursor   = (int*)alloc((size_t)N_NODES * 4);
    float* dinv     = (float*)alloc((size_t)N_NODES * 4);
    int*   col      = (int*)alloc((size_t)N_EDGES * 4);
    unsigned short* hs = (unsigned short*)alloc((size_t)N_NODES * OUT_F * 2);
    float* partialT = (float*)alloc((size_t)512 * ABLOCKS * 4);
    float* ss       = (float*)alloc(512 * 4);
    int*   excl     = (int*)alloc((size_t)N_NODES * 4);
    int*   blocksum = (int*)alloc(64 * 4);
    unsigned short* wpk  = (unsigned short*)alloc((size_t)4 * 16 * 64 * 8 * 2);
    unsigned short* wppk = (unsigned short*)alloc((size_t)4 * 16 * 64 * 8 * 2);
    if (off > ws_size) return;   // workspace too small: fail loudly (poisoned output)

    const int* srcp = ei;
    const int* dstp = ei + N_EDGES;

    hipMemsetAsync(cnt, 0, (size_t)N_NODES * 4, stream);
    pack_kernel<<<32, 256, 0, stream>>>(W, Wp, wpk, wppk);
    count_kernel<<<(N_EDGES + 255) / 256, 256, 0, stream>>>(dstp, cnt, N_EDGES);
    scan1_kernel<<<SCAN_NB, 256, 0, stream>>>(cnt, excl, blocksum, N_NODES);
    scan3_kernel<<<(N_NODES + 255) / 256, 256, 0, stream>>>(cnt, excl, blocksum,
                                                            rowptr, cursor, dinv, N_NODES);
    fill_kernel<<<(N_EDGES + 255) / 256, 256, 0, stream>>>(srcp, dstp, cursor, col, N_EDGES);

    int gblocks = (N_NODES + 63) / 64;   // 782
    mgemm_kernel<0><<<gblocks, 256, 0, stream>>>(x, wpk, dinv, hs, nullptr, nullptr);

    agg_kernel<<<ABLOCKS, 256, 0, stream>>>(hs, rowptr, col, dinv, out, partialT, ABLOCKS * 4);

    stats2_kernel<<<256, 256, 0, stream>>>(partialT, gamma, beta, ss);

    mgemm_kernel<1><<<gblocks, 256, 0, stream>>>(x, wppk, nullptr, nullptr, ss, out);
}

// Round 13
// 306.186 us; speedup vs baseline: 1.0705x; 1.0705x over previous
//
#include <hip/hip_runtime.h>
#include <hip/hip_bf16.h>

#define N_NODES 50000
#define N_EDGES 800000
#define IN_F    128
#define OUT_F   256
#define BN_EPS  1e-5f
#define ABLOCKS 2048
#define SCAN_NB ((N_NODES + 1023) / 1024)   // 49

typedef float float4_ __attribute__((ext_vector_type(4)));
typedef float f32x4 __attribute__((ext_vector_type(4)));
typedef short bf16x8 __attribute__((ext_vector_type(8)));
typedef unsigned int uint4_ __attribute__((ext_vector_type(4)));

// ---------------- CSR build ----------------

__global__ void count_kernel(const int* __restrict__ dst, int* __restrict__ cnt, int e) {
    int i = blockIdx.x * blockDim.x + threadIdx.x;
    if (i < e) atomicAdd(&cnt[dst[i]], 1);
}

// hierarchical scan, level 1: per-block (1024 elems) exclusive prefix + block total
__global__ __launch_bounds__(256) void scan1_kernel(const int* __restrict__ cnt,
        int* __restrict__ excl, int* __restrict__ blocksum, int n) {
    __shared__ int wsum[4];
    int tid = threadIdx.x;
    int lane = tid & 63, wv = tid >> 6;
    int base = blockIdx.x * 1024 + tid * 4;
    int v0 = (base + 0 < n) ? cnt[base + 0] : 0;
    int v1 = (base + 1 < n) ? cnt[base + 1] : 0;
    int v2 = (base + 2 < n) ? cnt[base + 2] : 0;
    int v3 = (base + 3 < n) ? cnt[base + 3] : 0;
    int t = v0 + v1 + v2 + v3;
    int s = t;
    #pragma unroll
    for (int d = 1; d < 64; d <<= 1) {
        int o = __shfl_up(s, d, 64);
        if (lane >= d) s += o;
    }
    if (lane == 63) wsum[wv] = s;
    __syncthreads();
    int woff = 0;
    #pragma unroll
    for (int w = 0; w < 4; w++) woff += (w < wv) ? wsum[w] : 0;
    int off = woff + s - t;   // exclusive prefix for this thread's first elem
    if (base + 0 < n) excl[base + 0] = off;
    if (base + 1 < n) excl[base + 1] = off + v0;
    if (base + 2 < n) excl[base + 2] = off + v0 + v1;
    if (base + 3 < n) excl[base + 3] = off + v0 + v1 + v2;
    if (tid == 255) blocksum[blockIdx.x] = woff + s;
}

// level 2+3 fused: every block redundantly wave-scans the 49 block sums,
// then emits rowptr/cursor/dinv.
__global__ __launch_bounds__(256) void scan3_kernel(const int* __restrict__ cnt,
        const int* __restrict__ excl, const int* __restrict__ blocksum,
        int* __restrict__ rowptr, int* __restrict__ cursor, float* __restrict__ dinv, int n) {
    __shared__ int boff_s, total_s;
    int tid = threadIdx.x;
    if (tid < 64) {
        int v = (tid < SCAN_NB) ? blocksum[tid] : 0;
        int s = v;
        #pragma unroll
        for (int d = 1; d < 64; d <<= 1) {
            int o = __shfl_up(s, d, 64);
            if (tid >= d) s += o;
        }
        if (tid == (blockIdx.x >> 2)) boff_s = s - v;   // this block's 1024-chunk offset
        if (tid == SCAN_NB - 1) total_s = s;
    }
    __syncthreads();
    int i = blockIdx.x * 256 + tid;
    if (i < n) {
        int r = excl[i] + boff_s;
        rowptr[i] = r;
        cursor[i] = r;
        dinv[i] = rsqrtf((float)(cnt[i] + 1));
    }
    if (i == 0) rowptr[n] = total_s;
}

__global__ void fill_kernel(const int* __restrict__ src, const int* __restrict__ dst,
                            int* __restrict__ cursor, int* __restrict__ col, int e) {
    int i = blockIdx.x * blockDim.x + threadIdx.x;
    if (i < e) {
        int d = dst[i];
        int pos = atomicAdd(&cursor[d], 1);
        col[pos] = src[i];
    }
}

// ---------------- bf16 helpers ----------------

__device__ inline unsigned short f2bf(float f) {
    union { float f; unsigned int u; } a; a.f = f;
    unsigned int u = a.u;
    unsigned int r = (u + 0x7FFFu + ((u >> 16) & 1u)) >> 16;
    return (unsigned short)r;
}

// ---------------- W / Wp pack for MFMA B-operand ----------------
// wpk[((kb*16 + nt)*64 + lane)*8 + j] = bf16( W[kb*32 + (lane>>4)*8 + j][nt*16 + (lane&15)] )
// B-frag layout for mfma_f32_16x16x32_bf16: lane l holds B[k=(l>>4)*8+j][col=l&15].

__global__ void pack_kernel(const float* __restrict__ W, const float* __restrict__ Wp,
                            unsigned short* __restrict__ wpk, unsigned short* __restrict__ wppk) {
    int b = blockIdx.x;   // 32 blocks: 0-15 -> W, 16-31 -> Wp
    const float* src = (b < 16) ? W : Wp;
    unsigned short* dst = (b < 16) ? wpk : wppk;
    int base = (b & 15) * 2048;
    for (int t = threadIdx.x; t < 2048; t += 256) {
        int idx = base + t;
        int j = idx & 7, l = (idx >> 3) & 63, nt = (idx >> 9) & 15, kb = idx >> 13;
        int k = kb * 32 + ((l >> 4) << 3) + j;
        int c = (nt << 4) + (l & 15);
        dst[idx] = f2bf(src[k * 256 + c]);
    }
}

// ---------------- MFMA GEMM: wave = 16 rows x 256 cols, K=128 ----------------
// MODE 0: hs[r][c] = bf16( dinv[r] * (x@W)[r][c] )
// MODE 1: out[r][c] = relu( out[r][c]*scale[c] + shift[c] ) + (x@Wp)[r][c]   (in-place)

template <int MODE>
__global__ __launch_bounds__(256) void mgemm_kernel(
    const float* __restrict__ X, const unsigned short* __restrict__ wpk,
    const float* __restrict__ dinv, unsigned short* __restrict__ hs,
    const float* __restrict__ ss, float* __restrict__ out)
{
    int wv = threadIdx.x >> 6;
    int lane = threadIdx.x & 63;
    int r0 = blockIdx.x * 64 + wv * 16;
    if (r0 >= N_NODES) return;

    int arow = min(r0 + (lane & 15), N_NODES - 1);
    int kbase = (lane >> 4) << 3;   // 0,8,16,24

    union Frag { bf16x8 v; unsigned int u[4]; uint4_ q; };

    // load + convert A fragments (once per wave, reused across all 16 n-tiles)
    Frag af[4];
    const float* xrow = X + (size_t)arow * IN_F + kbase;
    #pragma unroll
    for (int kb = 0; kb < 4; kb++) {
        float4_ p0 = *(const float4_*)(xrow + kb * 32);
        float4_ p1 = *(const float4_*)(xrow + kb * 32 + 4);
        af[kb].u[0] = (unsigned int)f2bf(p0[0]) | ((unsigned int)f2bf(p0[1]) << 16);
        af[kb].u[1] = (unsigned int)f2bf(p0[2]) | ((unsigned int)f2bf(p0[3]) << 16);
        af[kb].u[2] = (unsigned int)f2bf(p1[0]) | ((unsigned int)f2bf(p1[1]) << 16);
        af[kb].u[3] = (unsigned int)f2bf(p1[2]) | ((unsigned int)f2bf(p1[3]) << 16);
    }

    int rb = r0 + ((lane >> 4) << 2);   // C/D row base for this lane
    float dv[4];
    if (MODE == 0) {
        #pragma unroll
        for (int g = 0; g < 4; g++) dv[g] = dinv[min(rb + g, N_NODES - 1)];
    }

    for (int nt = 0; nt < 16; nt++) {
        f32x4 acc = (f32x4){0.f, 0.f, 0.f, 0.f};
        #pragma unroll
        for (int kb = 0; kb < 4; kb++) {
            Frag bf;
            bf.q = *(const uint4_*)(wpk + (((kb * 16 + nt) * 64 + lane) << 3));
            acc = __builtin_amdgcn_mfma_f32_16x16x32_bf16(af[kb].v, bf.v, acc, 0, 0, 0);
        }
        int colb = (nt << 4) + (lane & 15);
        if (MODE == 0) {
            #pragma unroll
            for (int g = 0; g < 4; g++) {
                int r = rb + g;
                if (r < N_NODES) hs[(size_t)r * OUT_F + colb] = f2bf(acc[g] * dv[g]);
            }
        } else {
            float sc = ss[colb], sh = ss[OUT_F + colb];
            #pragma unroll
            for (int g = 0; g < 4; g++) {
                int r = rb + g;
                if (r < N_NODES) {
                    float* p = out + (size_t)r * OUT_F + colb;
                    float v = *p;
                    *p = fmaxf(v * sc + sh, 0.f) + acc[g];
                }
            }
        }
    }
}

// ---------------- CSR aggregation ----------------
// R8-proven structure: 1 full wave per node, lane owns feats [4l,4l+4) (8 B uint2
// loads, 512 B contiguous per wave), 4 independent accumulate chains.
// Fused BN partial stats; partial written CONTIGUOUS per block
// ( partial[block*512 + t] — full-line writes; the R11/R12 transposed scatter
//   caused ~41 MB of partial-line writeback amplification ).

__global__ __launch_bounds__(256) void agg_kernel(
    const unsigned short* __restrict__ hrow, const int* __restrict__ rowptr,
    const int* __restrict__ col, const float* __restrict__ dinv,
    float* __restrict__ out, float* __restrict__ partial, int nwaves_total)
{
    __shared__ float lds_s[4][512];
    int wv = threadIdx.x >> 6;
    int wid = blockIdx.x * 4 + wv;
    int lane = threadIdx.x & 63;

    f32x4 psum = (f32x4){0.f, 0.f, 0.f, 0.f};
    f32x4 pssq = (f32x4){0.f, 0.f, 0.f, 0.f};

    auto loadrow = [&](int r) -> float4_ {
        uint2 u = *(const uint2*)(hrow + (size_t)r * 256 + lane * 4);
        float4_ f;
        f[0] = __uint_as_float(u.x << 16);
        f[1] = __uint_as_float(u.x & 0xFFFF0000u);
        f[2] = __uint_as_float(u.y << 16);
        f[3] = __uint_as_float(u.y & 0xFFFF0000u);
        return f;
    };

    for (int i = wid; i < N_NODES; i += nwaves_total) {
        float4_ a0 = loadrow(i);            // self-loop term
        float4_ a1 = (float4_){0.f, 0.f, 0.f, 0.f};
        float4_ a2 = (float4_){0.f, 0.f, 0.f, 0.f};
        float4_ a3 = (float4_){0.f, 0.f, 0.f, 0.f};
        int rs = rowptr[i], re = rowptr[i + 1];
        int j = rs;
        for (; j + 3 < re; j += 4) {
            int c0 = col[j], c1 = col[j + 1], c2 = col[j + 2], c3 = col[j + 3];
            a0 += loadrow(c0);
            a1 += loadrow(c1);
            a2 += loadrow(c2);
            a3 += loadrow(c3);
        }
        for (; j < re; j++) a0 += loadrow(col[j]);
        a0 += a1; a2 += a3; a0 += a2;
        float dv = dinv[i];
        float4_ c = a0 * dv;
        psum += c;
        pssq += c * c;
        ((float4_*)out)[(size_t)i * 64 + lane] = c;
    }

    // per-wave stats into LDS: lane owns feats [4*lane, 4*lane+4)
    #pragma unroll
    for (int k = 0; k < 4; k++) {
        lds_s[wv][lane * 4 + k] = psum[k];
        lds_s[wv][256 + lane * 4 + k] = pssq[k];
    }
    __syncthreads();
    int t = threadIdx.x;
    float s0 = lds_s[0][t] + lds_s[1][t] + lds_s[2][t] + lds_s[3][t];
    float s1 = lds_s[0][256 + t] + lds_s[1][256 + t] + lds_s[2][256 + t] + lds_s[3][256 + t];
    partial[(size_t)blockIdx.x * 512 + t] = s0;
    partial[(size_t)blockIdx.x * 512 + 256 + t] = s1;
}

// ---------------- BN stats reduce: block f -> ss[f], ss[256+f] ----------------

__global__ __launch_bounds__(256) void stats2_kernel(const float* __restrict__ partial,
        const float* __restrict__ gamma, const float* __restrict__ beta,
        float* __restrict__ ss) {
    int f = blockIdx.x;
    int t = threadIdx.x;
    float ps = 0.f, qs = 0.f;
    for (int r = t; r < ABLOCKS; r += 256) {
        ps += partial[(size_t)r * 512 + f];
        qs += partial[(size_t)r * 512 + 256 + f];
    }
    __shared__ float rs_[256], rq_[256];
    rs_[t] = ps; rq_[t] = qs;
    __syncthreads();
    for (int off = 128; off > 0; off >>= 1) {
        if (t < off) { rs_[t] += rs_[t + off]; rq_[t] += rq_[t + off]; }
        __syncthreads();
    }
    if (t == 0) {
        float mean = rs_[0] / (float)N_NODES;
        float var = rq_[0] / (float)N_NODES - mean * mean;
        float inv = rsqrtf(var + BN_EPS);
        float sc = gamma[f] * inv;
        ss[f] = sc;
        ss[256 + f] = beta[f] - mean * sc;
    }
}

// ---------------- launch ----------------

extern "C" void kernel_launch(void* const* d_in, const int* in_sizes, int n_in,
                              void* d_out, int out_size, void* d_ws, size_t ws_size,
                              hipStream_t stream) {
    const float* x     = (const float*)d_in[0];
    const int*   ei    = (const int*)d_in[1];
    const float* W     = (const float*)d_in[2];
    // d_in[3] = b : cancels under BatchNorm, unused
    const float* gamma = (const float*)d_in[4];
    const float* beta  = (const float*)d_in[5];
    const float* Wp    = (const float*)d_in[6];
    float* out = (float*)d_out;

    char* wsp = (char*)d_ws;
    size_t off = 0;
    auto alloc = [&](size_t sz) -> void* {
        void* p = wsp + off;
        off += (sz + 255) & ~(size_t)255;
        return p;
    };
    int*   cnt      = (int*)alloc((size_t)N_NODES * 4);
    int*   rowptr   = (int*)alloc((size_t)(N_NODES + 1) * 4);
    int*   cursor   = (int*)alloc((size_t)N_NODES * 4);
    float* dinv     = (float*)alloc((size_t)N_NODES * 4);
    int*   col      = (int*)alloc((size_t)N_EDGES * 4);
    unsigned short* hs = (unsigned short*)alloc((size_t)N_NODES * OUT_F * 2);
    float* partial  = (float*)alloc((size_t)ABLOCKS * 512 * 4);
    float* ss       = (float*)alloc(512 * 4);
    int*   excl     = (int*)alloc((size_t)N_NODES * 4);
    int*   blocksum = (int*)alloc(64 * 4);
    unsigned short* wpk  = (unsigned short*)alloc((size_t)4 * 16 * 64 * 8 * 2);
    unsigned short* wppk = (unsigned short*)alloc((size_t)4 * 16 * 64 * 8 * 2);
    if (off > ws_size) return;   // workspace too small: fail loudly (poisoned output)

    const int* srcp = ei;
    const int* dstp = ei + N_EDGES;

    hipMemsetAsync(cnt, 0, (size_t)N_NODES * 4, stream);
    pack_kernel<<<32, 256, 0, stream>>>(W, Wp, wpk, wppk);
    count_kernel<<<(N_EDGES + 255) / 256, 256, 0, stream>>>(dstp, cnt, N_EDGES);
    scan1_kernel<<<SCAN_NB, 256, 0, stream>>>(cnt, excl, blocksum, N_NODES);
    scan3_kernel<<<(N_NODES + 255) / 256, 256, 0, stream>>>(cnt, excl, blocksum,
                                                            rowptr, cursor, dinv, N_NODES);
    fill_kernel<<<(N_EDGES + 255) / 256, 256, 0, stream>>>(srcp, dstp, cursor, col, N_EDGES);

    int gblocks = (N_NODES + 63) / 64;   // 782
    mgemm_kernel<0><<<gblocks, 256, 0, stream>>>(x, wpk, dinv, hs, nullptr, nullptr);

    agg_kernel<<<ABLOCKS, 256, 0, stream>>>(hs, rowptr, col, dinv, out, partial, ABLOCKS * 4);

    stats2_kernel<<<256, 256, 0, stream>>>(partial, gamma, beta, ss);

    mgemm_kernel<1><<<gblocks, 256, 0, stream>>>(x, wppk, nullptr, nullptr, ss, out);
}

// Round 14
// 287.844 us; speedup vs baseline: 1.1387x; 1.0637x over previous
//
#include <hip/hip_runtime.h>
#include <hip/hip_bf16.h>

#define N_NODES 50000
#define N_EDGES 800000
#define IN_F    128
#define OUT_F   256
#define BN_EPS  1e-5f
#define ABLOCKS 2048
#define SCAN_NB ((N_NODES + 1023) / 1024)   // 49

typedef float float4_ __attribute__((ext_vector_type(4)));
typedef float f32x4 __attribute__((ext_vector_type(4)));
typedef short bf16x8 __attribute__((ext_vector_type(8)));
typedef unsigned int uint4_ __attribute__((ext_vector_type(4)));

// ---------------- CSR build ----------------

__global__ void count_kernel(const int* __restrict__ dst, int* __restrict__ cnt, int e) {
    int i = blockIdx.x * blockDim.x + threadIdx.x;
    if (i < e) atomicAdd(&cnt[dst[i]], 1);
}

// hierarchical scan, level 1: per-block (1024 elems) exclusive prefix + block total
__global__ __launch_bounds__(256) void scan1_kernel(const int* __restrict__ cnt,
        int* __restrict__ excl, int* __restrict__ blocksum, int n) {
    __shared__ int wsum[4];
    int tid = threadIdx.x;
    int lane = tid & 63, wv = tid >> 6;
    int base = blockIdx.x * 1024 + tid * 4;
    int v0 = (base + 0 < n) ? cnt[base + 0] : 0;
    int v1 = (base + 1 < n) ? cnt[base + 1] : 0;
    int v2 = (base + 2 < n) ? cnt[base + 2] : 0;
    int v3 = (base + 3 < n) ? cnt[base + 3] : 0;
    int t = v0 + v1 + v2 + v3;
    int s = t;
    #pragma unroll
    for (int d = 1; d < 64; d <<= 1) {
        int o = __shfl_up(s, d, 64);
        if (lane >= d) s += o;
    }
    if (lane == 63) wsum[wv] = s;
    __syncthreads();
    int woff = 0;
    #pragma unroll
    for (int w = 0; w < 4; w++) woff += (w < wv) ? wsum[w] : 0;
    int off = woff + s - t;   // exclusive prefix for this thread's first elem
    if (base + 0 < n) excl[base + 0] = off;
    if (base + 1 < n) excl[base + 1] = off + v0;
    if (base + 2 < n) excl[base + 2] = off + v0 + v1;
    if (base + 3 < n) excl[base + 3] = off + v0 + v1 + v2;
    if (tid == 255) blocksum[blockIdx.x] = woff + s;
}

// level 2+3 fused: every block redundantly wave-scans the 49 block sums,
// then emits rowptr/cursor/dinv.
__global__ __launch_bounds__(256) void scan3_kernel(const int* __restrict__ cnt,
        const int* __restrict__ excl, const int* __restrict__ blocksum,
        int* __restrict__ rowptr, int* __restrict__ cursor, float* __restrict__ dinv, int n) {
    __shared__ int boff_s, total_s;
    int tid = threadIdx.x;
    if (tid < 64) {
        int v = (tid < SCAN_NB) ? blocksum[tid] : 0;
        int s = v;
        #pragma unroll
        for (int d = 1; d < 64; d <<= 1) {
            int o = __shfl_up(s, d, 64);
            if (tid >= d) s += o;
        }
        if (tid == (blockIdx.x >> 2)) boff_s = s - v;   // this block's 1024-chunk offset
        if (tid == SCAN_NB - 1) total_s = s;
    }
    __syncthreads();
    int i = blockIdx.x * 256 + tid;
    if (i < n) {
        int r = excl[i] + boff_s;
        rowptr[i] = r;
        cursor[i] = r;
        dinv[i] = rsqrtf((float)(cnt[i] + 1));
    }
    if (i == 0) rowptr[n] = total_s;
}

__global__ void fill_kernel(const int* __restrict__ src, const int* __restrict__ dst,
                            int* __restrict__ cursor, int* __restrict__ col, int e) {
    int i = blockIdx.x * blockDim.x + threadIdx.x;
    if (i < e) {
        int d = dst[i];
        int pos = atomicAdd(&cursor[d], 1);
        col[pos] = src[i];
    }
}

// ---------------- bf16 helpers ----------------

__device__ inline unsigned short f2bf(float f) {
    union { float f; unsigned int u; } a; a.f = f;
    unsigned int u = a.u;
    unsigned int r = (u + 0x7FFFu + ((u >> 16) & 1u)) >> 16;
    return (unsigned short)r;
}

// ---------------- W / Wp pack for MFMA B-operand ----------------
// wpk[((kb*16 + nt)*64 + lane)*8 + j] = bf16( W[kb*32 + (lane>>4)*8 + j][nt*16 + (lane&15)] )
// B-frag layout for mfma_f32_16x16x32_bf16: lane l holds B[k=(l>>4)*8+j][col=l&15].

__global__ void pack_kernel(const float* __restrict__ W, const float* __restrict__ Wp,
                            unsigned short* __restrict__ wpk, unsigned short* __restrict__ wppk) {
    int b = blockIdx.x;   // 32 blocks: 0-15 -> W, 16-31 -> Wp
    const float* src = (b < 16) ? W : Wp;
    unsigned short* dst = (b < 16) ? wpk : wppk;
    int base = (b & 15) * 2048;
    for (int t = threadIdx.x; t < 2048; t += 256) {
        int idx = base + t;
        int j = idx & 7, l = (idx >> 3) & 63, nt = (idx >> 9) & 15, kb = idx >> 13;
        int k = kb * 32 + ((l >> 4) << 3) + j;
        int c = (nt << 4) + (l & 15);
        dst[idx] = f2bf(src[k * 256 + c]);
    }
}

// ---------------- Fused MFMA GEMM: hs = bf16(dinv*(x@W)), p = bf16(x@Wp) ----------------
// Shares A-fragments between both GEMMs (x read+converted once).
// A-frag: lane l holds x[row = r0 + (l&15)][k = kb*32 + (l>>4)*8 + j], j=0..7
// C/D:    lane l holds D[row = r0 + (l>>4)*4 + g][col = nt*16 + (l&15)], g = reg 0..3

__global__ __launch_bounds__(256) void mgemmF_kernel(
    const float* __restrict__ X, const unsigned short* __restrict__ wpk,
    const unsigned short* __restrict__ wppk, const float* __restrict__ dinv,
    unsigned short* __restrict__ hs, unsigned short* __restrict__ p)
{
    int wv = threadIdx.x >> 6;
    int lane = threadIdx.x & 63;
    int r0 = blockIdx.x * 64 + wv * 16;
    if (r0 >= N_NODES) return;

    int arow = min(r0 + (lane & 15), N_NODES - 1);
    int kbase = (lane >> 4) << 3;   // 0,8,16,24

    union Frag { bf16x8 v; unsigned int u[4]; uint4_ q; };

    Frag af[4];
    const float* xrow = X + (size_t)arow * IN_F + kbase;
    #pragma unroll
    for (int kb = 0; kb < 4; kb++) {
        float4_ p0 = *(const float4_*)(xrow + kb * 32);
        float4_ p1 = *(const float4_*)(xrow + kb * 32 + 4);
        af[kb].u[0] = (unsigned int)f2bf(p0[0]) | ((unsigned int)f2bf(p0[1]) << 16);
        af[kb].u[1] = (unsigned int)f2bf(p0[2]) | ((unsigned int)f2bf(p0[3]) << 16);
        af[kb].u[2] = (unsigned int)f2bf(p1[0]) | ((unsigned int)f2bf(p1[1]) << 16);
        af[kb].u[3] = (unsigned int)f2bf(p1[2]) | ((unsigned int)f2bf(p1[3]) << 16);
    }

    int rb = r0 + ((lane >> 4) << 2);   // C/D row base for this lane
    float dv[4];
    #pragma unroll
    for (int g = 0; g < 4; g++) dv[g] = dinv[min(rb + g, N_NODES - 1)];

    for (int nt = 0; nt < 16; nt++) {
        f32x4 accW = (f32x4){0.f, 0.f, 0.f, 0.f};
        f32x4 accP = (f32x4){0.f, 0.f, 0.f, 0.f};
        #pragma unroll
        for (int kb = 0; kb < 4; kb++) {
            Frag bw, bp;
            bw.q = *(const uint4_*)(wpk  + (((kb * 16 + nt) * 64 + lane) << 3));
            bp.q = *(const uint4_*)(wppk + (((kb * 16 + nt) * 64 + lane) << 3));
            accW = __builtin_amdgcn_mfma_f32_16x16x32_bf16(af[kb].v, bw.v, accW, 0, 0, 0);
            accP = __builtin_amdgcn_mfma_f32_16x16x32_bf16(af[kb].v, bp.v, accP, 0, 0, 0);
        }
        int colb = (nt << 4) + (lane & 15);
        #pragma unroll
        for (int g = 0; g < 4; g++) {
            int r = rb + g;
            if (r < N_NODES) {
                hs[(size_t)r * OUT_F + colb] = f2bf(accW[g] * dv[g]);
                p [(size_t)r * OUT_F + colb] = f2bf(accP[g]);
            }
        }
    }
}

// ---------------- CSR aggregation ----------------
// R13-proven gather: 1 full wave per node, lane owns feats [4l,4l+4) (8 B uint2
// loads), 4 independent accumulate chains. Output now bf16 (aggb) -> halves the
// agg write traffic; BN stats from the f32 values pre-rounding.
// partial written CONTIGUOUS per block (R13 lesson: strided 4B scatter = ~41 MB
// partial-line writeback amplification).

__global__ __launch_bounds__(256) void agg_kernel(
    const unsigned short* __restrict__ hrow, const int* __restrict__ rowptr,
    const int* __restrict__ col, const float* __restrict__ dinv,
    unsigned short* __restrict__ aggb, float* __restrict__ partial, int nwaves_total)
{
    __shared__ float lds_s[4][512];
    int wv = threadIdx.x >> 6;
    int wid = blockIdx.x * 4 + wv;
    int lane = threadIdx.x & 63;

    f32x4 psum = (f32x4){0.f, 0.f, 0.f, 0.f};
    f32x4 pssq = (f32x4){0.f, 0.f, 0.f, 0.f};

    auto loadrow = [&](int r) -> float4_ {
        uint2 u = *(const uint2*)(hrow + (size_t)r * 256 + lane * 4);
        float4_ f;
        f[0] = __uint_as_float(u.x << 16);
        f[1] = __uint_as_float(u.x & 0xFFFF0000u);
        f[2] = __uint_as_float(u.y << 16);
        f[3] = __uint_as_float(u.y & 0xFFFF0000u);
        return f;
    };

    for (int i = wid; i < N_NODES; i += nwaves_total) {
        float4_ a0 = loadrow(i);            // self-loop term
        float4_ a1 = (float4_){0.f, 0.f, 0.f, 0.f};
        float4_ a2 = (float4_){0.f, 0.f, 0.f, 0.f};
        float4_ a3 = (float4_){0.f, 0.f, 0.f, 0.f};
        int rs = rowptr[i], re = rowptr[i + 1];
        int j = rs;
        for (; j + 3 < re; j += 4) {
            int c0 = col[j], c1 = col[j + 1], c2 = col[j + 2], c3 = col[j + 3];
            a0 += loadrow(c0);
            a1 += loadrow(c1);
            a2 += loadrow(c2);
            a3 += loadrow(c3);
        }
        for (; j < re; j++) a0 += loadrow(col[j]);
        a0 += a1; a2 += a3; a0 += a2;
        float dv = dinv[i];
        float4_ c = a0 * dv;
        psum += c;
        pssq += c * c;
        uint2 pk;
        pk.x = (unsigned int)f2bf(c[0]) | ((unsigned int)f2bf(c[1]) << 16);
        pk.y = (unsigned int)f2bf(c[2]) | ((unsigned int)f2bf(c[3]) << 16);
        *(uint2*)(aggb + (size_t)i * OUT_F + lane * 4) = pk;
    }

    // per-wave stats into LDS: lane owns feats [4*lane, 4*lane+4)
    #pragma unroll
    for (int k = 0; k < 4; k++) {
        lds_s[wv][lane * 4 + k] = psum[k];
        lds_s[wv][256 + lane * 4 + k] = pssq[k];
    }
    __syncthreads();
    int t = threadIdx.x;
    float s0 = lds_s[0][t] + lds_s[1][t] + lds_s[2][t] + lds_s[3][t];
    float s1 = lds_s[0][256 + t] + lds_s[1][256 + t] + lds_s[2][256 + t] + lds_s[3][256 + t];
    partial[(size_t)blockIdx.x * 512 + t] = s0;
    partial[(size_t)blockIdx.x * 512 + 256 + t] = s1;
}

// ---------------- BN stats reduce: block f -> ss[f], ss[256+f] ----------------

__global__ __launch_bounds__(256) void stats2_kernel(const float* __restrict__ partial,
        const float* __restrict__ gamma, const float* __restrict__ beta,
        float* __restrict__ ss) {
    int f = blockIdx.x;
    int t = threadIdx.x;
    float ps = 0.f, qs = 0.f;
    for (int r = t; r < ABLOCKS; r += 256) {
        ps += partial[(size_t)r * 512 + f];
        qs += partial[(size_t)r * 512 + 256 + f];
    }
    __shared__ float rs_[256], rq_[256];
    rs_[t] = ps; rq_[t] = qs;
    __syncthreads();
    for (int off = 128; off > 0; off >>= 1) {
        if (t < off) { rs_[t] += rs_[t + off]; rq_[t] += rq_[t + off]; }
        __syncthreads();
    }
    if (t == 0) {
        float mean = rs_[0] / (float)N_NODES;
        float var = rq_[0] / (float)N_NODES - mean * mean;
        float inv = rsqrtf(var + BN_EPS);
        float sc = gamma[f] * inv;
        ss[f] = sc;
        ss[256 + f] = beta[f] - mean * sc;
    }
}

// ---------------- epilogue: out = relu(aggb*sc+sh) + p  (pure streaming) ----------------
// thread handles 8 contiguous feats; 6250 blocks x 256 threads x 8 = 12.8M elems exact.

__global__ __launch_bounds__(256) void epi_kernel(const unsigned short* __restrict__ aggb,
        const unsigned short* __restrict__ p, const float* __restrict__ ss,
        float* __restrict__ out) {
    size_t base = ((size_t)blockIdx.x * 256 + threadIdx.x) * 8;
    int f = (int)(base & 255);
    uint4_ qa = *(const uint4_*)(aggb + base);
    uint4_ qp = *(const uint4_*)(p + base);
    float4_ sc0 = *(const float4_*)(ss + f);
    float4_ sc1 = *(const float4_*)(ss + f + 4);
    float4_ sh0 = *(const float4_*)(ss + OUT_F + f);
    float4_ sh1 = *(const float4_*)(ss + OUT_F + f + 4);
    float4_ r0, r1;
    #pragma unroll
    for (int k = 0; k < 4; k++) {
        unsigned int ua = qa[k], up = qp[k];
        float a0 = __uint_as_float(ua << 16);
        float a1 = __uint_as_float(ua & 0xFFFF0000u);
        float p0 = __uint_as_float(up << 16);
        float p1 = __uint_as_float(up & 0xFFFF0000u);
        float4_& sc = (k < 2) ? sc0 : sc1;
        float4_& sh = (k < 2) ? sh0 : sh1;
        int b = (k & 1) * 2;
        float v0 = fmaxf(a0 * sc[b]     + sh[b],     0.f) + p0;
        float v1 = fmaxf(a1 * sc[b + 1] + sh[b + 1], 0.f) + p1;
        if (k < 2) { r0[k * 2] = v0; r0[k * 2 + 1] = v1; }
        else       { r1[(k - 2) * 2] = v0; r1[(k - 2) * 2 + 1] = v1; }
    }
    *(float4_*)(out + base) = r0;
    *(float4_*)(out + base + 4) = r1;
}

// ---------------- launch ----------------

extern "C" void kernel_launch(void* const* d_in, const int* in_sizes, int n_in,
                              void* d_out, int out_size, void* d_ws, size_t ws_size,
                              hipStream_t stream) {
    const float* x     = (const float*)d_in[0];
    const int*   ei    = (const int*)d_in[1];
    const float* W     = (const float*)d_in[2];
    // d_in[3] = b : cancels under BatchNorm, unused
    const float* gamma = (const float*)d_in[4];
    const float* beta  = (const float*)d_in[5];
    const float* Wp    = (const float*)d_in[6];
    float* out = (float*)d_out;

    char* wsp = (char*)d_ws;
    size_t off = 0;
    auto alloc = [&](size_t sz) -> void* {
        void* p = wsp + off;
        off += (sz + 255) & ~(size_t)255;
        return p;
    };
    int*   cnt      = (int*)alloc((size_t)N_NODES * 4);
    int*   rowptr   = (int*)alloc((size_t)(N_NODES + 1) * 4);
    int*   cursor   = (int*)alloc((size_t)N_NODES * 4);
    float* dinv     = (float*)alloc((size_t)N_NODES * 4);
    int*   col      = (int*)alloc((size_t)N_EDGES * 4);
    unsigned short* hs   = (unsigned short*)alloc((size_t)N_NODES * OUT_F * 2);
    unsigned short* pbuf = (unsigned short*)alloc((size_t)N_NODES * OUT_F * 2);
    unsigned short* aggb = (unsigned short*)alloc((size_t)N_NODES * OUT_F * 2);
    float* partial  = (float*)alloc((size_t)ABLOCKS * 512 * 4);
    float* ss       = (float*)alloc(512 * 4);
    int*   excl     = (int*)alloc((size_t)N_NODES * 4);
    int*   blocksum = (int*)alloc(64 * 4);
    unsigned short* wpk  = (unsigned short*)alloc((size_t)4 * 16 * 64 * 8 * 2);
    unsigned short* wppk = (unsigned short*)alloc((size_t)4 * 16 * 64 * 8 * 2);
    if (off > ws_size) return;   // workspace too small: fail loudly (poisoned output)

    const int* srcp = ei;
    const int* dstp = ei + N_EDGES;

    hipMemsetAsync(cnt, 0, (size_t)N_NODES * 4, stream);
    pack_kernel<<<32, 256, 0, stream>>>(W, Wp, wpk, wppk);
    count_kernel<<<(N_EDGES + 255) / 256, 256, 0, stream>>>(dstp, cnt, N_EDGES);
    scan1_kernel<<<SCAN_NB, 256, 0, stream>>>(cnt, excl, blocksum, N_NODES);
    scan3_kernel<<<(N_NODES + 255) / 256, 256, 0, stream>>>(cnt, excl, blocksum,
                                                            rowptr, cursor, dinv, N_NODES);
    fill_kernel<<<(N_EDGES + 255) / 256, 256, 0, stream>>>(srcp, dstp, cursor, col, N_EDGES);

    int gblocks = (N_NODES + 63) / 64;   // 782
    mgemmF_kernel<<<gblocks, 256, 0, stream>>>(x, wpk, wppk, dinv, hs, pbuf);

    agg_kernel<<<ABLOCKS, 256, 0, stream>>>(hs, rowptr, col, dinv, aggb, partial, ABLOCKS * 4);

    stats2_kernel<<<256, 256, 0, stream>>>(partial, gamma, beta, ss);

    epi_kernel<<<(N_NODES * OUT_F) / 2048, 256, 0, stream>>>(aggb, pbuf, ss, out);
}